// Round 1
// baseline (924.293 us; speedup 1.0000x reference)
//
#include <hip/hip_runtime.h>
#include <hip/hip_bf16.h>

#define B_SZ    32768
#define LAT     1024
#define EMB     32
#define ZCB     8192
#define NSPLIT  4
#define CPS     (ZCB / NSPLIT)   /* 2048 codes per split */
#define CHUNK   256              /* codes staged in LDS per chunk */

/* d_out float offsets: out, loss, enc, cb, idx, ze */
#define OFF_OUT   0
#define OFF_LOSS  ((size_t)B_SZ * LAT)        /* 33554432 */
#define OFF_ENC   (OFF_LOSS + 1)
#define OFF_CB    (OFF_LOSS + 2)
#define OFF_IDX   (OFF_LOSS + 3)
#define OFF_ZE    (OFF_IDX + B_SZ)

/* ws float offsets */
#define WS_WN     0
#define WS_WNN    (ZCB * EMB)                    /* 262144 */
#define WS_PDIST  (WS_WNN + ZCB)                 /* 270336 */
#define WS_PIDX   (WS_PDIST + B_SZ * NSPLIT)     /* 401408 (int32) */
#define WS_ZST    (WS_PIDX + B_SZ * NSPLIT)      /* 532480 */
#define WS_ZE     (WS_ZST + B_SZ * EMB)          /* 1581056 (aligned ze copy) */
#define WS_LPART  (WS_ZE + B_SZ * EMB)           /* 2629632 */

/* ---------------- codebook normalize: wn, wnn ---------------- */
__global__ __launch_bounds__(256) void knorm(const float* __restrict__ cb,
                                             float* __restrict__ wn,
                                             float* __restrict__ wnn) {
    int e = threadIdx.x;             /* 0..31 */
    int r = threadIdx.y;             /* 0..7  */
    int row = blockIdx.x * 8 + r;
    float v = cb[row * EMB + e];
    float s = v * v;
    #pragma unroll
    for (int m = 16; m >= 1; m >>= 1) s += __shfl_xor(s, m, 64);
    float n = fmaxf(sqrtf(s), 1e-12f);
    float w = v / n;
    float s2 = w * w;
    #pragma unroll
    for (int m = 16; m >= 1; m >>= 1) s2 += __shfl_xor(s2, m, 64);
    wn[row * EMB + e] = w;
    if (e == 0) wnn[row] = s2;
}

/* ---------------- ze = z_e @ in_w^T + in_b ---------------- */
__global__ __launch_bounds__(256) void kze(const float* __restrict__ z_e,
                                           const float* __restrict__ in_w,
                                           const float* __restrict__ in_b,
                                           float* __restrict__ ze_out,     /* d_out region (scalar) */
                                           float* __restrict__ ze_ws) {    /* aligned copy */
    __shared__ float4 zs4[2048];     /* 8 rows x 1024 floats = 32 KB */
    int tid = threadIdx.x;
    size_t base_row = (size_t)blockIdx.x * 8;
    const float4* g4 = (const float4*)(z_e + base_row * LAT);
    #pragma unroll
    for (int i = 0; i < 8; ++i) zs4[tid + i * 256] = g4[tid + i * 256];
    __syncthreads();
    int r = tid >> 5, e = tid & 31;
    const float4* z4 = (const float4*)&zs4[r * 256];
    const float4* w4 = (const float4*)(in_w + (size_t)e * LAT);
    float a0=0,a1=0,a2=0,a3=0,a4=0,a5=0,a6=0,a7=0;
    #pragma unroll 4
    for (int k = 0; k < 128; ++k) {
        float4 z0 = z4[2*k], z1 = z4[2*k+1];
        float4 w0 = w4[2*k], w1 = w4[2*k+1];
        a0 = fmaf(z0.x, w0.x, a0); a1 = fmaf(z0.y, w0.y, a1);
        a2 = fmaf(z0.z, w0.z, a2); a3 = fmaf(z0.w, w0.w, a3);
        a4 = fmaf(z1.x, w1.x, a4); a5 = fmaf(z1.y, w1.y, a5);
        a6 = fmaf(z1.z, w1.z, a6); a7 = fmaf(z1.w, w1.w, a7);
    }
    float s = ((a0+a1)+(a2+a3)) + ((a4+a5)+(a6+a7)) + in_b[e];
    size_t o = base_row * EMB + tid;
    ze_out[o] = s;
    ze_ws[o]  = s;
}

/* ---------------- distance + partial argmin ---------------- */
__global__ __launch_bounds__(256) void kdist(const float* __restrict__ ze,
                                             const float* __restrict__ wn,
                                             const float* __restrict__ wnn,
                                             float* __restrict__ pdist,
                                             int* __restrict__ pidx) {
    __shared__ float wch[CHUNK * EMB];   /* 32 KB */
    __shared__ float wnch[CHUNK];
    int tid = threadIdx.x;
    int row = blockIdx.x * 256 + tid;
    int split = blockIdx.y;

    float zr[32];
    const float4* z4 = (const float4*)(ze + (size_t)row * EMB);
    #pragma unroll
    for (int i = 0; i < 8; ++i) {
        float4 v = z4[i];
        zr[4*i]=v.x; zr[4*i+1]=v.y; zr[4*i+2]=v.z; zr[4*i+3]=v.w;
    }
    float nn = 0.f;
    #pragma unroll
    for (int i = 0; i < 32; ++i) nn = fmaf(zr[i], zr[i], nn);
    float n = fmaxf(sqrtf(nn), 1e-12f);
    #pragma unroll
    for (int i = 0; i < 32; ++i) zr[i] /= n;

    float best = 1e30f; int bidx = 0;
    int j0base = split * CPS;
    for (int c = 0; c < CPS / CHUNK; ++c) {
        int j0 = j0base + c * CHUNK;
        __syncthreads();
        {
            const float4* src = (const float4*)(wn + (size_t)j0 * EMB);
            float4* dst = (float4*)wch;
            #pragma unroll
            for (int i = 0; i < 8; ++i) dst[tid + i * 256] = src[tid + i * 256];
            if (tid < CHUNK) wnch[tid] = wnn[j0 + tid];
        }
        __syncthreads();
        #pragma unroll 2
        for (int j = 0; j < CHUNK; ++j) {
            const float4* wv = (const float4*)&wch[j * EMB];  /* wave-uniform -> broadcast */
            float s0=0,s1=0,s2=0,s3=0;
            #pragma unroll
            for (int k = 0; k < 8; ++k) {
                float4 w = wv[k];
                s0 = fmaf(zr[4*k],   w.x, s0);
                s1 = fmaf(zr[4*k+1], w.y, s1);
                s2 = fmaf(zr[4*k+2], w.z, s2);
                s3 = fmaf(zr[4*k+3], w.w, s3);
            }
            float s = (s0 + s1) + (s2 + s3);
            float r = fmaf(-2.f, s, wnch[j]);   /* znn const per row: drop it */
            if (r < best) { best = r; bidx = j0 + j; }
        }
    }
    pdist[split * B_SZ + row] = best;
    pidx [split * B_SZ + row] = bidx;
}

/* ------- merge splits, idx, z_st, per-block loss partial ------- */
__global__ __launch_bounds__(256) void kmerge(const float* __restrict__ pdist,
                                              const int* __restrict__ pidx,
                                              const float* __restrict__ ze,
                                              const float* __restrict__ cb,
                                              float* __restrict__ out_idx,
                                              float* __restrict__ zst,
                                              float* __restrict__ lpart) {
    int tid = threadIdx.x;
    int row = blockIdx.x * 256 + tid;
    float best = pdist[row]; int bidx = pidx[row];
    #pragma unroll
    for (int s = 1; s < NSPLIT; ++s) {
        float d = pdist[(size_t)s * B_SZ + row];
        int ii  = pidx [(size_t)s * B_SZ + row];
        if (d < best) { best = d; bidx = ii; }   /* strict <: first-min tie-break */
    }
    out_idx[row] = (float)bidx;

    const float4* zq4 = (const float4*)(cb + (size_t)bidx * EMB);
    const float4* ze4 = (const float4*)(ze + (size_t)row * EMB);
    float4* zs4 = (float4*)(zst + (size_t)row * EMB);
    float sq = 0.f;
    #pragma unroll
    for (int i = 0; i < 8; ++i) {
        float4 q = zq4[i], z = ze4[i];
        float dx = z.x - q.x, dy = z.y - q.y, dz = z.z - q.z, dw = z.w - q.w;
        sq += (dx*dx + dy*dy) + (dz*dz + dw*dw);
        float4 o;
        o.x = z.x + (q.x - z.x); o.y = z.y + (q.y - z.y);
        o.z = z.z + (q.z - z.z); o.w = z.w + (q.w - z.w);
        zs4[i] = o;
    }
    #pragma unroll
    for (int m = 1; m <= 32; m <<= 1) sq += __shfl_xor(sq, m, 64);
    __shared__ float red[4];
    if ((tid & 63) == 0) red[tid >> 6] = sq;
    __syncthreads();
    if (tid == 0) lpart[blockIdx.x] = (red[0] + red[1]) + (red[2] + red[3]);
}

/* ---------------- losses ---------------- */
__global__ void kloss(const float* __restrict__ lpart, float* __restrict__ dout) {
    float v = lpart[threadIdx.x];   /* 128 threads */
    #pragma unroll
    for (int m = 1; m <= 32; m <<= 1) v += __shfl_xor(v, m, 64);
    __shared__ float tmp[2];
    if ((threadIdx.x & 63) == 0) tmp[threadIdx.x >> 6] = v;
    __syncthreads();
    if (threadIdx.x == 0) {
        float enc = (tmp[0] + tmp[1]) / (float)(B_SZ * EMB);
        dout[OFF_LOSS] = 1.0f * enc + 0.25f * enc;  /* CB_COST*cb + COMMIT*enc */
        dout[OFF_ENC]  = enc;
        dout[OFF_CB]   = enc;
    }
}

/* ---------------- out = z_st @ out_w^T + out_b ---------------- */
__global__ __launch_bounds__(256) void kout(const float* __restrict__ zst,
                                            const float* __restrict__ out_w,
                                            const float* __restrict__ out_b,
                                            float* __restrict__ out) {
    int tid = threadIdx.x;
    int col = blockIdx.x * 512 + tid * 2;
    float wa[32], wb[32];
    const float4* wa4 = (const float4*)(out_w + (size_t)col * EMB);
    const float4* wb4 = (const float4*)(out_w + (size_t)(col + 1) * EMB);
    #pragma unroll
    for (int i = 0; i < 8; ++i) {
        float4 a = wa4[i]; wa[4*i]=a.x; wa[4*i+1]=a.y; wa[4*i+2]=a.z; wa[4*i+3]=a.w;
        float4 b = wb4[i]; wb[4*i]=b.x; wb[4*i+1]=b.y; wb[4*i+2]=b.z; wb[4*i+3]=b.w;
    }
    float b0 = out_b[col], b1 = out_b[col + 1];
    size_t r0 = (size_t)blockIdx.y * 128;
    for (int rr = 0; rr < 128; ++rr) {
        size_t row = r0 + rr;
        const float* zs = zst + row * EMB;   /* uniform per row -> scalar loads */
        float a0 = b0, a1 = b1;
        #pragma unroll
        for (int e = 0; e < 32; ++e) {
            float z = zs[e];
            a0 = fmaf(z, wa[e], a0);
            a1 = fmaf(z, wb[e], a1);
        }
        float2 o; o.x = a0; o.y = a1;
        *(float2*)(out + row * LAT + col) = o;
    }
}

extern "C" void kernel_launch(void* const* d_in, const int* in_sizes, int n_in,
                              void* d_out, int out_size, void* d_ws, size_t ws_size,
                              hipStream_t stream) {
    const float* z_e   = (const float*)d_in[0];
    const float* in_w  = (const float*)d_in[1];
    const float* in_b  = (const float*)d_in[2];
    const float* out_w = (const float*)d_in[3];
    const float* out_b = (const float*)d_in[4];
    const float* cb    = (const float*)d_in[5];

    float* out  = (float*)d_out;
    float* ws   = (float*)d_ws;
    float* wn    = ws + WS_WN;
    float* wnn   = ws + WS_WNN;
    float* pdist = ws + WS_PDIST;
    int*   pidx  = (int*)(ws + WS_PIDX);
    float* zst   = ws + WS_ZST;
    float* ze_ws = ws + WS_ZE;
    float* lpart = ws + WS_LPART;

    knorm <<<dim3(ZCB / 8), dim3(32, 8), 0, stream>>>(cb, wn, wnn);
    kze   <<<dim3(B_SZ / 8), 256, 0, stream>>>(z_e, in_w, in_b, out + OFF_ZE, ze_ws);
    kdist <<<dim3(B_SZ / 256, NSPLIT), 256, 0, stream>>>(ze_ws, wn, wnn, pdist, pidx);
    kmerge<<<dim3(B_SZ / 256), 256, 0, stream>>>(pdist, pidx, ze_ws, cb, out + OFF_IDX, zst, lpart);
    kloss <<<1, 128, 0, stream>>>(lpart, out);
    kout  <<<dim3(2, B_SZ / 128), 256, 0, stream>>>(zst, out_w, out_b, out);
}

// Round 2
// 368.749 us; speedup vs baseline: 2.5066x; 2.5066x over previous
//
#include <hip/hip_runtime.h>
#include <hip/hip_bf16.h>

#define B_SZ    32768
#define LAT     1024
#define EMB     32
#define ZCB     8192
#define NSPLIT  8
#define CPS     (ZCB / NSPLIT)   /* 1024 codes per split */
#define CHUNK   256              /* codes staged in LDS per chunk */

/* d_out float offsets: out, loss, enc, cb, idx, ze */
#define OFF_LOSS  ((size_t)B_SZ * LAT)        /* 33554432 */
#define OFF_ENC   (OFF_LOSS + 1)
#define OFF_CB    (OFF_LOSS + 2)
#define OFF_IDX   (OFF_LOSS + 3)
#define OFF_ZE    (OFF_IDX + B_SZ)

/* ws float offsets */
#define WS_WN     0
#define WS_WNN    (ZCB * EMB)                    /* 262144 */
#define WS_PDIST  (WS_WNN + ZCB)                 /* 270336 */
#define WS_PIDX   (WS_PDIST + B_SZ * NSPLIT)     /* 532480 (int32) */
#define WS_ZST    (WS_PIDX + B_SZ * NSPLIT)      /* 794624 */
#define WS_ZE     (WS_ZST + B_SZ * EMB)          /* 1843200 */
#define WS_PZE    (WS_ZE + B_SZ * EMB)           /* 2891776, 2x B*EMB */
#define WS_LPART  (WS_PZE + 2 * B_SZ * EMB)      /* 4988928 */

/* ---------------- codebook normalize: wn, wnn ---------------- */
__global__ __launch_bounds__(256) void knorm(const float* __restrict__ cb,
                                             float* __restrict__ wn,
                                             float* __restrict__ wnn) {
    int e = threadIdx.x;             /* 0..31 */
    int r = threadIdx.y;             /* 0..7  */
    int row = blockIdx.x * 8 + r;
    float v = cb[row * EMB + e];
    float s = v * v;
    #pragma unroll
    for (int m = 16; m >= 1; m >>= 1) s += __shfl_xor(s, m, 64);
    float n = fmaxf(sqrtf(s), 1e-12f);
    float w = v / n;
    float s2 = w * w;
    #pragma unroll
    for (int m = 16; m >= 1; m >>= 1) s2 += __shfl_xor(s2, m, 64);
    wn[row * EMB + e] = w;
    if (e == 0) wnn[row] = s2;
}

/* ---------------- ze partial GEMM: pze[ks][B][32] ---------------- */
#define KZB 64
#define KZS 68   /* zs row stride: 16B aligned; rows rs..rs+15 -> 2-way bank alias (free) */
__global__ __launch_bounds__(256) void kze2(const float* __restrict__ z_e,
                                            const float* __restrict__ in_w,
                                            float* __restrict__ pze) {
    __shared__ float zs[128 * KZS];   /* 34.8 KB */
    __shared__ float wt[KZB * 32];    /* 8 KB, transposed + xor-swizzled */
    int tid = threadIdx.x;
    size_t row0 = (size_t)blockIdx.x * 128;
    int ks = blockIdx.y;
    int rs = tid >> 2;        /* 0..63: rows rs, rs+64 */
    int eg = tid & 3;         /* 0..3: e-range eg*8..+7 */
    int E  = eg * 8;

    float acc[2][8];
    #pragma unroll
    for (int i = 0; i < 2; ++i)
        #pragma unroll
        for (int j = 0; j < 8; ++j) acc[i][j] = 0.f;

    for (int c = 0; c < 512 / KZB; ++c) {
        int kb = ks * 512 + c * KZB;
        __syncthreads();
        /* stage z tile: 128 rows x 64 cols = 2048 float4 (coalesced 256B/16 lanes) */
        #pragma unroll
        for (int i = 0; i < 8; ++i) {
            int t = tid + i * 256;
            int r = t >> 4, c4 = t & 15;
            float4 v = *(const float4*)(z_e + (row0 + r) * LAT + kb + c4 * 4);
            *(float4*)&zs[r * KZS + c4 * 4] = v;
        }
        /* stage w transposed: wt[k][e ^ 4*(k&7)] */
        #pragma unroll
        for (int i = 0; i < 2; ++i) {
            int t = tid + i * 256;
            int e = t >> 4, k4 = t & 15;
            float4 v = *(const float4*)(in_w + (size_t)e * LAT + kb + k4 * 4);
            float vv[4] = {v.x, v.y, v.z, v.w};
            #pragma unroll
            for (int j = 0; j < 4; ++j) {
                int k = k4 * 4 + j;
                wt[k * 32 + (e ^ ((k & 7) << 2))] = vv[j];
            }
        }
        __syncthreads();
        #pragma unroll 4
        for (int kq = 0; kq < KZB / 4; ++kq) {
            int k0 = kq * 4;
            float4 za = *(const float4*)&zs[rs * KZS + k0];
            float4 zb = *(const float4*)&zs[(rs + 64) * KZS + k0];
            float zav[4] = {za.x, za.y, za.z, za.w};
            float zbv[4] = {zb.x, zb.y, zb.z, zb.w};
            #pragma unroll
            for (int i = 0; i < 4; ++i) {
                int k = k0 + i;
                int sw = (k & 7) << 2;
                float4 w0 = *(const float4*)&wt[k * 32 + (E ^ sw)];
                float4 w1 = *(const float4*)&wt[k * 32 + ((E + 4) ^ sw)];
                float wa[8] = {w0.x, w0.y, w0.z, w0.w, w1.x, w1.y, w1.z, w1.w};
                #pragma unroll
                for (int j = 0; j < 8; ++j) {
                    acc[0][j] = fmaf(zav[i], wa[j], acc[0][j]);
                    acc[1][j] = fmaf(zbv[i], wa[j], acc[1][j]);
                }
            }
        }
    }
    size_t rb = ((size_t)ks * B_SZ + row0);
    float* p0 = pze + (rb + rs) * EMB + E;
    float* p1 = pze + (rb + rs + 64) * EMB + E;
    *(float4*)p0       = make_float4(acc[0][0], acc[0][1], acc[0][2], acc[0][3]);
    *(float4*)(p0 + 4) = make_float4(acc[0][4], acc[0][5], acc[0][6], acc[0][7]);
    *(float4*)p1       = make_float4(acc[1][0], acc[1][1], acc[1][2], acc[1][3]);
    *(float4*)(p1 + 4) = make_float4(acc[1][4], acc[1][5], acc[1][6], acc[1][7]);
}

/* ---------------- merge K-splits + bias -> ze (d_out, scalar) + ze_ws ---------------- */
__global__ __launch_bounds__(256) void kzemerge(const float* __restrict__ pze,
                                                const float* __restrict__ in_b,
                                                float* __restrict__ out_ze,
                                                float* __restrict__ ze_ws) {
    __shared__ float bsh[32];
    int tid = threadIdx.x;
    if (tid < 32) bsh[tid] = in_b[tid];
    __syncthreads();
    const float* p0 = pze;
    const float* p1 = pze + (size_t)B_SZ * EMB;
    size_t q0 = (size_t)blockIdx.x * 512;
    #pragma unroll
    for (int i = 0; i < 2; ++i) {
        size_t q = q0 + i * 256 + tid;
        float4 a = ((const float4*)p0)[q];
        float4 b = ((const float4*)p1)[q];
        int eb = (int)(q & 7) * 4;
        float4 o;
        o.x = a.x + b.x + bsh[eb];
        o.y = a.y + b.y + bsh[eb + 1];
        o.z = a.z + b.z + bsh[eb + 2];
        o.w = a.w + b.w + bsh[eb + 3];
        ((float4*)ze_ws)[q] = o;
    }
    size_t s0 = (size_t)blockIdx.x * 2048;
    #pragma unroll
    for (int i = 0; i < 8; ++i) {
        size_t s = s0 + i * 256 + tid;
        out_ze[s] = p0[s] + p1[s] + bsh[s & 31];
    }
}

/* ---------------- distance + partial argmin (2 rows/thread) ---------------- */
__global__ __launch_bounds__(256) void kdist(const float* __restrict__ ze,
                                             const float* __restrict__ wn,
                                             const float* __restrict__ wnn,
                                             float* __restrict__ pdist,
                                             int* __restrict__ pidx) {
    __shared__ float wch[CHUNK * EMB];   /* 32 KB */
    __shared__ float wnch[CHUNK];
    int tid = threadIdx.x;
    int row0 = blockIdx.x * 512;
    int split = blockIdx.y;
    int r0 = row0 + tid, r1 = row0 + 256 + tid;

    float za[32], zb[32];
    {
        const float4* z4 = (const float4*)(ze + (size_t)r0 * EMB);
        #pragma unroll
        for (int i = 0; i < 8; ++i) {
            float4 v = z4[i];
            za[4*i] = v.x; za[4*i+1] = v.y; za[4*i+2] = v.z; za[4*i+3] = v.w;
        }
        const float4* w4 = (const float4*)(ze + (size_t)r1 * EMB);
        #pragma unroll
        for (int i = 0; i < 8; ++i) {
            float4 v = w4[i];
            zb[4*i] = v.x; zb[4*i+1] = v.y; zb[4*i+2] = v.z; zb[4*i+3] = v.w;
        }
        float na = 0.f, nb = 0.f;
        #pragma unroll
        for (int i = 0; i < 32; ++i) { na = fmaf(za[i], za[i], na); nb = fmaf(zb[i], zb[i], nb); }
        na = fmaxf(sqrtf(na), 1e-12f);
        nb = fmaxf(sqrtf(nb), 1e-12f);
        #pragma unroll
        for (int i = 0; i < 32; ++i) { za[i] /= na; zb[i] /= nb; }
    }

    float best0 = 1e30f, best1 = 1e30f;
    int bi0 = 0, bi1 = 0;
    for (int c = 0; c < CPS / CHUNK; ++c) {
        int j0 = split * CPS + c * CHUNK;
        __syncthreads();
        {
            const float4* src = (const float4*)(wn + (size_t)j0 * EMB);
            float4* dst = (float4*)wch;
            #pragma unroll
            for (int i = 0; i < 8; ++i) dst[tid + i * 256] = src[tid + i * 256];
            wnch[tid] = wnn[j0 + tid];
        }
        __syncthreads();
        #pragma unroll 2
        for (int j = 0; j < CHUNK; ++j) {
            const float4* wv = (const float4*)&wch[j * EMB];  /* wave-uniform -> broadcast */
            float s0=0,s1=0,s2=0,s3=0, t0=0,t1=0,t2=0,t3=0;
            #pragma unroll
            for (int k = 0; k < 8; ++k) {
                float4 w = wv[k];
                s0 = fmaf(za[4*k],   w.x, s0);
                s1 = fmaf(za[4*k+1], w.y, s1);
                s2 = fmaf(za[4*k+2], w.z, s2);
                s3 = fmaf(za[4*k+3], w.w, s3);
                t0 = fmaf(zb[4*k],   w.x, t0);
                t1 = fmaf(zb[4*k+1], w.y, t1);
                t2 = fmaf(zb[4*k+2], w.z, t2);
                t3 = fmaf(zb[4*k+3], w.w, t3);
            }
            float wj = wnch[j];
            float da = fmaf(-2.f, (s0 + s1) + (s2 + s3), wj);
            float db = fmaf(-2.f, (t0 + t1) + (t2 + t3), wj);
            if (da < best0) { best0 = da; bi0 = j0 + j; }
            if (db < best1) { best1 = db; bi1 = j0 + j; }
        }
    }
    pdist[(size_t)split * B_SZ + r0] = best0;
    pidx [(size_t)split * B_SZ + r0] = bi0;
    pdist[(size_t)split * B_SZ + r1] = best1;
    pidx [(size_t)split * B_SZ + r1] = bi1;
}

/* ------- merge splits, idx, z_st, per-block loss partial ------- */
__global__ __launch_bounds__(256) void kmerge(const float* __restrict__ pdist,
                                              const int* __restrict__ pidx,
                                              const float* __restrict__ ze,
                                              const float* __restrict__ cb,
                                              float* __restrict__ out_idx,
                                              float* __restrict__ zst,
                                              float* __restrict__ lpart) {
    int tid = threadIdx.x;
    int row = blockIdx.x * 256 + tid;
    float best = pdist[row]; int bidx = pidx[row];
    #pragma unroll
    for (int s = 1; s < NSPLIT; ++s) {
        float d = pdist[(size_t)s * B_SZ + row];
        int ii  = pidx [(size_t)s * B_SZ + row];
        if (d < best) { best = d; bidx = ii; }   /* strict <: first-min tie-break */
    }
    out_idx[row] = (float)bidx;

    const float4* zq4 = (const float4*)(cb + (size_t)bidx * EMB);
    const float4* ze4 = (const float4*)(ze + (size_t)row * EMB);
    float4* zs4 = (float4*)(zst + (size_t)row * EMB);
    float sq = 0.f;
    #pragma unroll
    for (int i = 0; i < 8; ++i) {
        float4 q = zq4[i], z = ze4[i];
        float dx = z.x - q.x, dy = z.y - q.y, dz = z.z - q.z, dw = z.w - q.w;
        sq += (dx*dx + dy*dy) + (dz*dz + dw*dw);
        float4 o;
        o.x = z.x + (q.x - z.x); o.y = z.y + (q.y - z.y);
        o.z = z.z + (q.z - z.z); o.w = z.w + (q.w - z.w);
        zs4[i] = o;
    }
    #pragma unroll
    for (int m = 1; m <= 32; m <<= 1) sq += __shfl_xor(sq, m, 64);
    __shared__ float red[4];
    if ((tid & 63) == 0) red[tid >> 6] = sq;
    __syncthreads();
    if (tid == 0) lpart[blockIdx.x] = (red[0] + red[1]) + (red[2] + red[3]);
}

/* ---------------- losses ---------------- */
__global__ void kloss(const float* __restrict__ lpart, float* __restrict__ dout) {
    float v = lpart[threadIdx.x];   /* 128 threads */
    #pragma unroll
    for (int m = 1; m <= 32; m <<= 1) v += __shfl_xor(v, m, 64);
    __shared__ float tmp[2];
    if ((threadIdx.x & 63) == 0) tmp[threadIdx.x >> 6] = v;
    __syncthreads();
    if (threadIdx.x == 0) {
        float enc = (tmp[0] + tmp[1]) / (float)(B_SZ * EMB);
        dout[OFF_LOSS] = 1.0f * enc + 0.25f * enc;
        dout[OFF_ENC]  = enc;
        dout[OFF_CB]   = enc;
    }
}

/* ---------------- out = z_st @ out_w^T + out_b ---------------- */
__global__ __launch_bounds__(256) void kout(const float* __restrict__ zst,
                                            const float* __restrict__ out_w,
                                            const float* __restrict__ out_b,
                                            float* __restrict__ out) {
    __shared__ float zsh[128 * EMB];   /* 16 KB */
    int tid = threadIdx.x;
    int col = blockIdx.x * 512 + tid * 2;
    size_t row0 = (size_t)blockIdx.y * 128;
    /* stage zst tile: 1024 float4 */
    {
        const float4* src = (const float4*)(zst + row0 * EMB);
        float4* dst = (float4*)zsh;
        #pragma unroll
        for (int i = 0; i < 4; ++i) dst[tid + i * 256] = src[tid + i * 256];
    }
    float wa[32], wb[32];
    {
        const float4* wa4 = (const float4*)(out_w + (size_t)col * EMB);
        const float4* wb4 = (const float4*)(out_w + (size_t)(col + 1) * EMB);
        #pragma unroll
        for (int i = 0; i < 8; ++i) {
            float4 a = wa4[i]; wa[4*i]=a.x; wa[4*i+1]=a.y; wa[4*i+2]=a.z; wa[4*i+3]=a.w;
            float4 b = wb4[i]; wb[4*i]=b.x; wb[4*i+1]=b.y; wb[4*i+2]=b.z; wb[4*i+3]=b.w;
        }
    }
    float b0 = out_b[col], b1 = out_b[col + 1];
    __syncthreads();
    for (int rr = 0; rr < 128; ++rr) {
        const float4* zr4 = (const float4*)(zsh + rr * EMB);  /* uniform -> broadcast */
        float a0 = b0, a1 = b1;
        #pragma unroll
        for (int q = 0; q < 8; ++q) {
            float4 z = zr4[q];
            a0 = fmaf(z.x, wa[4*q],   a0); a1 = fmaf(z.x, wb[4*q],   a1);
            a0 = fmaf(z.y, wa[4*q+1], a0); a1 = fmaf(z.y, wb[4*q+1], a1);
            a0 = fmaf(z.z, wa[4*q+2], a0); a1 = fmaf(z.z, wb[4*q+2], a1);
            a0 = fmaf(z.w, wa[4*q+3], a0); a1 = fmaf(z.w, wb[4*q+3], a1);
        }
        float2 o; o.x = a0; o.y = a1;
        *(float2*)(out + (row0 + rr) * LAT + col) = o;
    }
}

extern "C" void kernel_launch(void* const* d_in, const int* in_sizes, int n_in,
                              void* d_out, int out_size, void* d_ws, size_t ws_size,
                              hipStream_t stream) {
    const float* z_e   = (const float*)d_in[0];
    const float* in_w  = (const float*)d_in[1];
    const float* in_b  = (const float*)d_in[2];
    const float* out_w = (const float*)d_in[3];
    const float* out_b = (const float*)d_in[4];
    const float* cb    = (const float*)d_in[5];

    float* out = (float*)d_out;
    float* ws  = (float*)d_ws;
    float* wn    = ws + WS_WN;
    float* wnn   = ws + WS_WNN;
    float* pdist = ws + WS_PDIST;
    int*   pidx  = (int*)(ws + WS_PIDX);
    float* zst   = ws + WS_ZST;
    float* ze_ws = ws + WS_ZE;
    float* pze   = ws + WS_PZE;
    float* lpart = ws + WS_LPART;

    knorm   <<<dim3(ZCB / 8), dim3(32, 8), 0, stream>>>(cb, wn, wnn);
    kze2    <<<dim3(B_SZ / 128, 2), 256, 0, stream>>>(z_e, in_w, pze);
    kzemerge<<<dim3(512), 256, 0, stream>>>(pze, in_b, out + OFF_ZE, ze_ws);
    kdist   <<<dim3(B_SZ / 512, NSPLIT), 256, 0, stream>>>(ze_ws, wn, wnn, pdist, pidx);
    kmerge  <<<dim3(B_SZ / 256), 256, 0, stream>>>(pdist, pidx, ze_ws, cb, out + OFF_IDX, zst, lpart);
    kloss   <<<1, 128, 0, stream>>>(lpart, out);
    kout    <<<dim3(2, B_SZ / 128), 256, 0, stream>>>(zst, out_w, out_b, out);
}